// Round 22
// baseline (512.441 us; speedup 1.0000x reference)
//
#include <hip/hip_runtime.h>
#include <hip/hip_bf16.h>

#define NLAT 511
#define NLON 512
#define LMAX 511
#define MMAX 257
#define KS 2                    // k-split factor
#define A_PER_M 16352           // floats: 511*32
#define P_PER_M 32768           // floats: KS*32*512

typedef unsigned short u16;
typedef unsigned int u32;

__device__ __forceinline__ u16 f2bf(float a) {
    __hip_bfloat16 h = __float2bfloat16(a);
    return *reinterpret_cast<u16*>(&h);
}

// ws layout per m-chunk of width MC:
//   A[mi][k][j]  (j = c*16 + ri*8 + b)            — MC * 16,352 f
//   P[(mi*KS+ks)*32 + jout][512]  planar partials — MC * 32,768 f
//   jout = cout*16 + ri*8 + b  (s0r: b, s0i: 8+b, s1r: 16+b, s1i: 24+b)

// ---------------------------------------------------------------------------
// Kernel 1: radix-2 LDS FFT per (ring, comp) — unchanged (verified).
// ---------------------------------------------------------------------------
__global__ __launch_bounds__(256) void fft3(const float* __restrict__ x,
                                            float* __restrict__ A,
                                            int m_lo, int m_hi) {
    const int kb   = blockIdx.x;       // 0..1021
    const int klat = kb >> 1;          // ring
    const int c    = kb & 1;           // vector component
    const int t    = threadIdx.x;

    __shared__ __align__(16) float re[8][512];
    __shared__ __align__(16) float im[8][512];

    #pragma unroll
    for (int b = 0; b < 8; ++b) {
        const float* row = x + ((size_t)(b * 2 + c) * NLAT + klat) * NLON;
        #pragma unroll
        for (int h = 0; h < 2; ++h) {
            int n  = h * 256 + t;
            int rn = (int)(__brev((u32)n) >> 23);   // 9-bit reversal
            re[b][rn] = row[n];
            im[b][rn] = 0.0f;
        }
    }
    __syncthreads();

    for (int s = 1; s <= 9; ++s) {
        const int half = 1 << (s - 1);
        const int j    = t & (half - 1);
        const int p0   = ((t >> (s - 1)) << s) + j;
        const int p1   = p0 + half;
        float sn, cs;
        sincosf(-6.28318530717958647692f * (float)j / (float)(1 << s), &sn, &cs);
        #pragma unroll
        for (int b = 0; b < 8; ++b) {
            float ar = re[b][p0], ai = im[b][p0];
            float br = re[b][p1], bi = im[b][p1];
            float tr = fmaf(br, cs, -bi * sn);
            float ti = fmaf(br, sn,  bi * cs);
            re[b][p0] = ar + tr;  im[b][p0] = ai + ti;
            re[b][p1] = ar - tr;  im[b][p1] = ai - ti;
        }
        __syncthreads();
    }

    for (int m = m_lo + t; m < m_hi; m += 256) {
        float4* d4 = (float4*)(A + ((size_t)(m - m_lo) * NLAT + klat) * 32 + c * 16);
        d4[0] = make_float4(re[0][m], re[1][m], re[2][m], re[3][m]);
        d4[1] = make_float4(re[4][m], re[5][m], re[6][m], re[7][m]);
        d4[2] = make_float4(im[0][m], im[1][m], im[2][m], im[3][m]);
        d4[3] = make_float4(im[4][m], im[5][m], im[6][m], im[7][m]);
    }
}

// ---------------------------------------------------------------------------
// Kernel 2: k-split Legendre partials.  Block = (mi, l-half, ks); 4x the
// blocks of R21 -> 4 waves/SIMD.  w loaded in 16-k (64 B) register bursts
// (each L1 line fully consumed within one burst -> no thrash).  A via
// wave-uniform scalar loads.  Partials stored planar (lane-contiguous).
// ---------------------------------------------------------------------------
__global__ __launch_bounds__(256) void leg6(const float* __restrict__ A,
                                            const float* __restrict__ w,
                                            float* __restrict__ P,
                                            int m_lo) {
    const int bid   = blockIdx.x;
    const int ks    = bid & 1;
    const int lhalf = (bid >> 1) & 1;
    const int mi    = bid >> 2;
    const int m     = m_lo + mi;
    const int t     = threadIdx.x;
    const int l     = lhalf * 256 + t;
    const int lc    = (l < LMAX) ? l : (LMAX - 1);

    const float* __restrict__ Am = A + (size_t)mi * A_PER_M;        // uniform
    const float* __restrict__ w0 = w + ((size_t)m * LMAX + lc) * NLAT;
    const float* __restrict__ w1 = w0 + (size_t)MMAX * LMAX * NLAT;

    const int kbeg = ks * 256;
    const int kend = ks ? NLAT : 256;

    float s0r[8] = {0}, s0i[8] = {0}, s1r[8] = {0}, s1i[8] = {0};

#define KSTEP(K, wA, wB)                                            \
    {                                                               \
        const float* Ak = Am + (size_t)(K) * 32;                    \
        _Pragma("unroll")                                           \
        for (int b = 0; b < 8; ++b) {                               \
            const float xr0 = Ak[b],      xi0 = Ak[8 + b];          \
            const float xr1 = Ak[16 + b], xi1 = Ak[24 + b];         \
            s0r[b] = fmaf(wA, xr0, fmaf(-wB, xi1, s0r[b]));         \
            s0i[b] = fmaf(wA, xi0, fmaf( wB, xr1, s0i[b]));         \
            s1r[b] = fmaf(-wB, xi0, fmaf(-wA, xr1, s1r[b]));        \
            s1i[b] = fmaf( wB, xr0, fmaf(-wA, xi1, s1i[b]));        \
        }                                                           \
    }

    int k0 = kbeg;
    for (; k0 + 16 <= kend; k0 += 16) {
        float wa[16], wb[16];
        #pragma unroll
        for (int i = 0; i < 16; ++i) {   // 64 B burst per row: line fully used
            wa[i] = w0[k0 + i];
            wb[i] = w1[k0 + i];
        }
        #pragma unroll
        for (int kk = 0; kk < 16; ++kk) KSTEP(k0 + kk, wa[kk], wb[kk])
    }
    // tail (ks=1: 15 k)
    for (int k = k0; k < kend; ++k) {
        const float wA = w0[k];
        const float wB = w1[k];
        KSTEP(k, wA, wB)
    }
#undef KSTEP

    // planar partial store: P[((mi*KS+ks)*32 + jout)*512 + l], lane-contiguous
    float* Pb = P + ((size_t)(mi * KS + ks) * 32) * 512 + l;
    #pragma unroll
    for (int b = 0; b < 8; ++b) {
        Pb[(size_t)(b)      * 512] = s0r[b];
        Pb[(size_t)(8 + b)  * 512] = s0i[b];
        Pb[(size_t)(16 + b) * 512] = s1r[b];
        Pb[(size_t)(24 + b) * 512] = s1i[b];
    }
}

// ---------------------------------------------------------------------------
// Kernel 3: reduce the KS partials, convert to bf16, store with +1 shift.
// ---------------------------------------------------------------------------
__global__ __launch_bounds__(256) void red6(const float* __restrict__ P,
                                            u16* __restrict__ out,
                                            int m_lo) {
    const int bid   = blockIdx.x;
    const int lhalf = bid & 1;
    const int mi    = bid >> 1;
    const int m     = m_lo + mi;
    const int t     = threadIdx.x;
    const int l     = lhalf * 256 + t;
    if (l >= LMAX) return;

    const float* P0 = P + ((size_t)(mi * KS + 0) * 32) * 512 + l;
    const float* P1 = P + ((size_t)(mi * KS + 1) * 32) * 512 + l;

    #pragma unroll
    for (int b = 0; b < 8; ++b) {
        const float s0r = P0[(size_t)(b)      * 512] + P1[(size_t)(b)      * 512];
        const float s0i = P0[(size_t)(8 + b)  * 512] + P1[(size_t)(8 + b)  * 512];
        const float s1r = P0[(size_t)(16 + b) * 512] + P1[(size_t)(16 + b) * 512];
        const float s1i = P0[(size_t)(24 + b) * 512] + P1[(size_t)(24 + b) * 512];
        const size_t c0 = ((size_t)(b * 2 + 0) * LMAX + l) * MMAX + m;
        const size_t c1 = ((size_t)(b * 2 + 1) * LMAX + l) * MMAX + m;
        // +1 SHIFT (measured R14-R17): validated flat[j] = our u16[j+1].
        out[2 * c0 + 1] = f2bf(s0r);
        out[2 * c0 + 2] = f2bf(s0i);
        out[2 * c1 + 1] = f2bf(s1r);
        out[2 * c1 + 2] = f2bf(s1i);
    }
}

extern "C" void kernel_launch(void* const* d_in, const int* in_sizes, int n_in,
                              void* d_out, int out_size, void* d_ws, size_t ws_size,
                              hipStream_t stream) {
    const float* x = (const float*)d_in[0];   // [8][2][511][512] f32
    const float* w = (const float*)d_in[1];   // [2][257][511][511] f32
    u16* out = (u16*)d_out;                   // bf16, validated at +2 B
    float* ws = (float*)d_ws;

    const size_t per_m = (size_t)(A_PER_M + P_PER_M) * sizeof(float); // 196,480 B
    int mchunk = (int)(ws_size / per_m);
    if (mchunk > MMAX) mchunk = MMAX;
    if (mchunk < 1) mchunk = 1;

    float* A = ws;
    float* P = ws + (size_t)mchunk * A_PER_M;

    for (int m0 = 0; m0 < MMAX; m0 += mchunk) {
        int m1 = m0 + mchunk;
        if (m1 > MMAX) m1 = MMAX;
        const int mc = m1 - m0;
        fft3<<<NLAT * 2, 256, 0, stream>>>(x, A, m0, m1);
        leg6<<<mc * 2 * KS, 256, 0, stream>>>(A, w, P, m0);
        red6<<<mc * 2, 256, 0, stream>>>(P, out, m0);
    }
}

// Round 23
// 378.436 us; speedup vs baseline: 1.3541x; 1.3541x over previous
//
#include <hip/hip_runtime.h>
#include <hip/hip_bf16.h>

#define NLAT 511
#define NLON 512
#define LMAX 511
#define MMAX 257
#define PAD 34              // A row stride in LDS floats: b64-aligned, 2-way banks

typedef unsigned short u16;
typedef unsigned int u32;

__device__ __forceinline__ u16 f2bf(float a) {
    __hip_bfloat16 h = __float2bfloat16(a);
    return *reinterpret_cast<u16*>(&h);
}

// A layout (f32, in d_ws): A[mi][k][j], j = c*16 + ri*8 + b.  Per-m: 65,408 B.

// ---------------------------------------------------------------------------
// Kernel 1: radix-2 LDS FFT per (ring, comp) — unchanged (verified).
// ---------------------------------------------------------------------------
__global__ __launch_bounds__(256) void fft3(const float* __restrict__ x,
                                            float* __restrict__ A,
                                            int m_lo, int m_hi) {
    const int kb   = blockIdx.x;       // 0..1021
    const int klat = kb >> 1;          // ring
    const int c    = kb & 1;           // vector component
    const int t    = threadIdx.x;

    __shared__ __align__(16) float re[8][512];
    __shared__ __align__(16) float im[8][512];

    #pragma unroll
    for (int b = 0; b < 8; ++b) {
        const float* row = x + ((size_t)(b * 2 + c) * NLAT + klat) * NLON;
        #pragma unroll
        for (int h = 0; h < 2; ++h) {
            int n  = h * 256 + t;
            int rn = (int)(__brev((u32)n) >> 23);   // 9-bit reversal
            re[b][rn] = row[n];
            im[b][rn] = 0.0f;
        }
    }
    __syncthreads();

    for (int s = 1; s <= 9; ++s) {
        const int half = 1 << (s - 1);
        const int j    = t & (half - 1);
        const int p0   = ((t >> (s - 1)) << s) + j;
        const int p1   = p0 + half;
        float sn, cs;
        sincosf(-6.28318530717958647692f * (float)j / (float)(1 << s), &sn, &cs);
        #pragma unroll
        for (int b = 0; b < 8; ++b) {
            float ar = re[b][p0], ai = im[b][p0];
            float br = re[b][p1], bi = im[b][p1];
            float tr = fmaf(br, cs, -bi * sn);
            float ti = fmaf(br, sn,  bi * cs);
            re[b][p0] = ar + tr;  im[b][p0] = ai + ti;
            re[b][p1] = ar - tr;  im[b][p1] = ai - ti;
        }
        __syncthreads();
    }

    for (int m = m_lo + t; m < m_hi; m += 256) {
        float4* d4 = (float4*)(A + ((size_t)(m - m_lo) * NLAT + klat) * 32 + c * 16);
        d4[0] = make_float4(re[0][m], re[1][m], re[2][m], re[3][m]);
        d4[1] = make_float4(re[4][m], re[5][m], re[6][m], re[7][m]);
        d4[2] = make_float4(im[0][m], im[1][m], im[2][m], im[3][m]);
        d4[3] = make_float4(im[4][m], im[5][m], im[6][m], im[7][m]);
    }
}

// ---------------------------------------------------------------------------
// Kernel 2: Legendre, lane = k (COALESCED w).  Block = (mi, l-group of 16);
// wave = 4 l; lanes cover 64 consecutive k per tile (8 tiles).
//  - w loads: 256 B contiguous per wave-instr  -> TA-cheap, FETCH-ideal.
//  - A[m] in LDS [k][PAD=34]; lane reads its k's 32 floats as 16 b64
//    (banks 2-way = free), amortized over 4 l.
//  - Per-l cross-lane reduce: in-LDS transpose (A buffer reused after
//    barrier) + shfl_xor(32); direct bf16 store with measured +1 shift.
// ---------------------------------------------------------------------------
__global__ __launch_bounds__(256, 2) void leg7(const float* __restrict__ A,
                                               const float* __restrict__ w,
                                               u16* __restrict__ out,
                                               int m_lo) {
    const int lg   = blockIdx.x & 31;          // l-group 0..31
    const int mi   = blockIdx.x >> 5;
    const int m    = m_lo + mi;
    const int t    = threadIdx.x;
    const int wid  = t >> 6;                   // wave 0..3
    const int lane = t & 63;

    __shared__ float As[NLAT * PAD];           // 69,496 B

    // stage A[mi] -> LDS (float2, coalesced reads)
    {
        const float2* src = (const float2*)(A + (size_t)mi * (NLAT * 32));
        for (int i = t; i < NLAT * 16; i += 256) {
            const int k = i >> 4, p = i & 15;
            *(float2*)&As[k * PAD + 2 * p] = src[i];
        }
    }
    __syncthreads();

    // this wave's 4 l rows
    const int l0 = lg * 16 + wid * 4;
    const float* w0r[4];
    const float* w1r[4];
    #pragma unroll
    for (int li = 0; li < 4; ++li) {
        const int l  = l0 + li;
        const int lc = (l < LMAX) ? l : (LMAX - 1);
        w0r[li] = w + ((size_t)m * LMAX + lc) * NLAT;
        w1r[li] = w0r[li] + (size_t)MMAX * LMAX * NLAT;
    }

    float acc[4][32];
    #pragma unroll
    for (int li = 0; li < 4; ++li)
        #pragma unroll
        for (int j = 0; j < 32; ++j) acc[li][j] = 0.0f;

    for (int tile = 0; tile < 8; ++tile) {
        const int myk  = tile * 64 + lane;
        const bool vk  = (myk < NLAT);
        const int kc   = vk ? myk : (NLAT - 1);

        float wa[4], wb[4];
        #pragma unroll
        for (int li = 0; li < 4; ++li) {       // coalesced 256 B wave loads
            const float va = w0r[li][kc];
            const float vb = w1r[li][kc];
            wa[li] = vk ? va : 0.0f;
            wb[li] = vk ? vb : 0.0f;
        }

        float Ak[32];
        {
            const float* base = &As[kc * PAD];
            #pragma unroll
            for (int p = 0; p < 16; ++p) {     // 16 x ds_read_b64, 2-way banks
                const float2 v = *(const float2*)&base[2 * p];
                Ak[2 * p]     = v.x;
                Ak[2 * p + 1] = v.y;
            }
        }

        #pragma unroll
        for (int li = 0; li < 4; ++li) {
            const float a = wa[li], g = wb[li];
            #pragma unroll
            for (int b = 0; b < 8; ++b) {
                acc[li][b]      = fmaf(a, Ak[b],      fmaf(-g, Ak[24 + b], acc[li][b]));
                acc[li][8 + b]  = fmaf(a, Ak[8 + b],  fmaf( g, Ak[16 + b], acc[li][8 + b]));
                acc[li][16 + b] = fmaf(-g, Ak[8 + b], fmaf(-a, Ak[16 + b], acc[li][16 + b]));
                acc[li][24 + b] = fmaf(g, Ak[b],      fmaf(-a, Ak[24 + b], acc[li][24 + b]));
            }
        }
    }

    // ---- per-l reduce across 64 lanes via LDS transpose (reuse As) ----
    float* red = As + wid * (64 * PAD);        // 8,704 B per wave, 4 waves fit
    const int o = lane & 31;
    const int h = lane >> 5;

    #pragma unroll
    for (int li = 0; li < 4; ++li) {
        __syncthreads();                       // k-loop done / prev reads done
        #pragma unroll
        for (int p = 0; p < 16; ++p)
            *(float2*)&red[lane * PAD + 2 * p] =
                make_float2(acc[li][2 * p], acc[li][2 * p + 1]);
        __syncthreads();                       // writes visible
        float s = 0.0f;
        #pragma unroll
        for (int i = 0; i < 32; ++i)           // banks (2i+o)%32: conflict-free
            s += red[(32 * h + i) * PAD + o];
        s += __shfl_xor(s, 32, 64);
        const int l = l0 + li;
        if (lane < 32 && l < LMAX) {
            const int cout = o >> 4, ri = (o >> 3) & 1, b = o & 7;
            const size_t cidx = ((size_t)(b * 2 + cout) * LMAX + l) * MMAX + m;
            // +1 SHIFT (measured R14-R17): validated flat[j] = our u16[j+1].
            out[2 * cidx + 1 + ri] = f2bf(s);
        }
    }
}

extern "C" void kernel_launch(void* const* d_in, const int* in_sizes, int n_in,
                              void* d_out, int out_size, void* d_ws, size_t ws_size,
                              hipStream_t stream) {
    const float* x = (const float*)d_in[0];   // [8][2][511][512] f32
    const float* w = (const float*)d_in[1];   // [2][257][511][511] f32
    u16* out = (u16*)d_out;                   // bf16, validated at +2 B
    float* A = (float*)d_ws;

    const size_t per_m = (size_t)NLAT * 32 * sizeof(float);   // 65,408 B
    int mchunk = (int)(ws_size / per_m);
    if (mchunk > MMAX) mchunk = MMAX;
    if (mchunk < 1) mchunk = 1;

    for (int m0 = 0; m0 < MMAX; m0 += mchunk) {
        int m1 = m0 + mchunk;
        if (m1 > MMAX) m1 = MMAX;
        const int mc = m1 - m0;
        fft3<<<NLAT * 2, 256, 0, stream>>>(x, A, m0, m1);
        leg7<<<mc * 32, 256, 0, stream>>>(A, w, out, m0);
    }
}